// Round 6
// baseline (222.038 us; speedup 1.0000x reference)
//
#include <hip/hip_runtime.h>
#include <hip/hip_bf16.h>
#include <cstdint>

#define B 32
#define D 8732
#define C 21
#define L 32
#define O 8
#define NW 273   // ceil(D/32) bitmask words
#define TILE 1024

struct Accum {
  double loss_l, loss_p, ce_pos, ce_neg, desk, trip_sum, trip_cnt;
  unsigned long long n_pp, n_np;
  int total_pos;
  int Pc;
};

__device__ inline double waveSumD(double v) {
  #pragma unroll
  for (int s = 32; s > 0; s >>= 1) v += __shfl_down(v, s, 64);
  return v;
}

__device__ inline float iou_one(float tx1, float ty1, float tx2, float ty2, float ta,
                                float px1, float py1, float px2, float py2, float areaB) {
  float lx = fmaxf(tx1, px1), ly = fmaxf(ty1, py1);
  float rx = fminf(tx2, px2), ry = fminf(ty2, py2);
  float iw = fmaxf(rx - lx, 0.f), ih = fmaxf(ry - ly, 0.f);
  float inter = iw * ih;
  return inter / (ta + areaB - inter);
}

// ============ K1: fully fused per-batch kernel ============
// one block (1024 thr) per batch. Phase 2 conf access is now LDS-tiled:
// coalesced float4 staging (4 lines/instr) instead of per-thread 84B-stride
// scalar gathers (64 lines/instr) — the R5 TA bottleneck.
__global__ __launch_bounds__(1024) void k_fused(
    const float* __restrict__ loc, const float* __restrict__ conf,
    const float* __restrict__ pose, const float* __restrict__ dbox,
    const float* __restrict__ targets,
    int* __restrict__ posBuf, int* __restrict__ posCnt, Accum* acc)
{
  int b = blockIdx.x;
  int tid = threadIdx.x;
  int lane = tid & 63, wav = tid >> 6;
  __shared__ __align__(16) float sce[D];        // 34928 B
  __shared__ __align__(16) float tile[TILE * C]; // 86016 B conf tile
  __shared__ int whist[16][256];                // 16384 B
  __shared__ int hist[256];
  __shared__ int sp[512];                       // scan buffer
  __shared__ unsigned pbits[NW];                // positive bitmask
  __shared__ float tb[O][4], ta[O], tl[O], tp_[O][3];
  __shared__ int bpd[O];
  __shared__ unsigned long long wm[16][O];
  __shared__ double wred[16][3];
  __shared__ unsigned sh_prefix;
  __shared__ int sh_k;
  __shared__ double wsum[16], wcnt[16];

  if (tid < O) {
    const float* tr = targets + ((size_t)b * O + tid) * 9;
    tb[tid][0] = tr[0]; tb[tid][1] = tr[1]; tb[tid][2] = tr[2]; tb[tid][3] = tr[3];
    ta[tid] = (tr[2] - tr[0]) * (tr[3] - tr[1]);
    tl[tid] = tr[4];
    tp_[tid][0] = tr[5]; tp_[tid][1] = tr[6]; tp_[tid][2] = tr[7];
  }
  for (int i = tid; i < NW; i += 1024) pbits[i] = 0;
  __syncthreads();

  // ---- phase 1: per-truth best prior (argmax over d, tie -> smaller d) ----
  unsigned long long key[O];
  #pragma unroll
  for (int t = 0; t < O; t++) key[t] = 0ull;
  for (int d = tid; d < D; d += 1024) {
    float4 db = *(const float4*)(dbox + (size_t)d * 4);
    float px1 = db.x - 0.5f*db.z, py1 = db.y - 0.5f*db.w;
    float px2 = db.x + 0.5f*db.z, py2 = db.y + 0.5f*db.w;
    float areaB = db.z * db.w;
    #pragma unroll
    for (int t = 0; t < O; t++) {
      float iou = iou_one(tb[t][0], tb[t][1], tb[t][2], tb[t][3], ta[t],
                          px1, py1, px2, py2, areaB);
      unsigned long long kk = ((unsigned long long)__float_as_uint(iou) << 32)
                            | (unsigned long long)(0xFFFFFFFFu - (unsigned)d);
      if (kk > key[t]) key[t] = kk;
    }
  }
  #pragma unroll
  for (int t = 0; t < O; t++) {
    unsigned long long k = key[t];
    #pragma unroll
    for (int s = 32; s > 0; s >>= 1) {
      unsigned long long o = __shfl_down(k, s, 64);
      if (o > k) k = o;
    }
    if (lane == 0) wm[wav][t] = k;
  }
  __syncthreads();
  if (tid < O) {
    unsigned long long k = wm[0][tid];
    #pragma unroll
    for (int w = 1; w < 16; w++) if (wm[w][tid] > k) k = wm[w][tid];
    bpd[tid] = (int)(0xFFFFFFFFu - (unsigned)(k & 0xFFFFFFFFull));
  }
  __syncthreads();

  // ---- phase 2: per-prior class, ce, loc/pose losses; conf via LDS tile ----
  double ll = 0, lp = 0, cp = 0;
  for (int base = 0; base < D; base += TILE) {
    int nd = D - base; if (nd > TILE) nd = TILE;
    // coalesced stage: nd*21 floats, always divisible by 4; base offsets 16B-aligned
    const float4* cb4 = (const float4*)(conf + ((size_t)b * D + base) * C);
    int n4 = nd * C / 4;
    __syncthreads();                     // protect tile from previous round's readers
    for (int i = tid; i < n4; i += 1024) ((float4*)tile)[i] = cb4[i];
    __syncthreads();
    int d = base + tid;
    if (tid < nd) {
      float4 db = *(const float4*)(dbox + (size_t)d * 4);
      float px1 = db.x - 0.5f*db.z, py1 = db.y - 0.5f*db.w;
      float px2 = db.x + 0.5f*db.z, py2 = db.y + 0.5f*db.w;
      float areaB = db.z * db.w;
      float bv = -1.0f; int bi = 0;
      #pragma unroll
      for (int t = 0; t < O; t++) {
        float iou = iou_one(tb[t][0], tb[t][1], tb[t][2], tb[t][3], ta[t],
                            px1, py1, px2, py2, areaB);
        if (iou > bv) { bv = iou; bi = t; }   // first max wins (argmax axis=0)
      }
      #pragma unroll
      for (int t = O - 1; t >= 0; t--)        // numpy scatter: last truth wins
        if (bpd[t] == d) { bi = t; bv = 2.0f; break; }
      int cls = (bv < 0.5f) ? 0 : ((int)tl[bi] + 1);
      const float* x = tile + tid * C;        // stride 21 (odd): 2-way alias, free
      float m = x[0];
      #pragma unroll
      for (int c = 1; c < C; c++) m = fmaxf(m, x[c]);
      float s = 0.f;
      #pragma unroll
      for (int c = 0; c < C; c++) s += __expf(x[c] - m);
      float ce = m + __logf(s) - x[cls];
      if (cls > 0) {
        cp += ce;
        sce[d] = 0.f;
        atomicOr(&pbits[d >> 5], 1u << (d & 31));
        float g0 = ((tb[bi][0] + tb[bi][2]) * 0.5f - db.x) / (0.1f * db.z);
        float g1 = ((tb[bi][1] + tb[bi][3]) * 0.5f - db.y) / (0.1f * db.w);
        float g2 = logf((tb[bi][2] - tb[bi][0]) / db.z) / 0.2f;
        float g3 = logf((tb[bi][3] - tb[bi][1]) / db.w) / 0.2f;
        size_t bd = (size_t)b * D + d;
        float4 lo = *(const float4*)(loc + bd * 4);
        float dv, a;
        dv = lo.x - g0; a = fabsf(dv); ll += (double)((a < 1.f) ? 0.5f*dv*dv : a - 0.5f);
        dv = lo.y - g1; a = fabsf(dv); ll += (double)((a < 1.f) ? 0.5f*dv*dv : a - 0.5f);
        dv = lo.z - g2; a = fabsf(dv); ll += (double)((a < 1.f) ? 0.5f*dv*dv : a - 0.5f);
        dv = lo.w - g3; a = fabsf(dv); ll += (double)((a < 1.f) ? 0.5f*dv*dv : a - 0.5f);
        const float* po = pose + bd * 3;
        #pragma unroll
        for (int q = 0; q < 3; q++) {
          float pd = po[q] - tp_[bi][q];
          lp += (double)pd * (double)pd;
        }
      } else {
        sce[d] = fmaxf(ce, 0.f);
      }
    }
  }
  double a0 = waveSumD(ll), a1 = waveSumD(lp), a2 = waveSumD(cp);
  if (lane == 0) { wred[wav][0] = a0; wred[wav][1] = a1; wred[wav][2] = a2; }
  __syncthreads();
  if (tid == 0) {
    double tll = 0, tlp = 0, tcp = 0;
    #pragma unroll
    for (int w = 0; w < 16; w++) { tll += wred[w][0]; tlp += wred[w][1]; tcp += wred[w][2]; }
    if (tll != 0.0) atomicAdd(&acc->loss_l, tll);
    if (tlp != 0.0) atomicAdd(&acc->loss_p, tlp);
    if (tcp != 0.0) atomicAdd(&acc->ce_pos, tcp);
  }

  // ---- phase 3: scan positive-bitmask popcounts; stable compaction ----
  if (tid < 512) sp[tid] = (tid < NW) ? (int)__popc(pbits[tid]) : 0;
  __syncthreads();
  for (int s = 1; s < 512; s <<= 1) {
    int v = 0;
    if (tid < 512) v = sp[tid] + ((tid >= s) ? sp[tid - s] : 0);
    __syncthreads();
    if (tid < 512) sp[tid] = v;
    __syncthreads();
  }
  int npos = sp[NW - 1];
  if (tid == 0) {
    posCnt[b] = (npos < 256) ? npos : 256;
    atomicAdd(&acc->total_pos, npos);
  }
  if (tid < NW) {
    unsigned w = pbits[tid];
    int base = sp[tid] - (int)__popc(w);     // exclusive prefix
    while (w) {
      int j = __ffs(w) - 1; w &= w - 1;
      int d = tid * 32 + j;
      int rank = base++;
      if (rank < 256) {
        float4 db = *(const float4*)(dbox + (size_t)d * 4);
        float px1 = db.x - 0.5f*db.z, py1 = db.y - 0.5f*db.w;
        float px2 = db.x + 0.5f*db.z, py2 = db.y + 0.5f*db.w;
        float areaB = db.z * db.w;
        float bv = -1.0f; int bi = 0;
        #pragma unroll
        for (int t = 0; t < O; t++) {
          float iou = iou_one(tb[t][0], tb[t][1], tb[t][2], tb[t][3], ta[t],
                              px1, py1, px2, py2, areaB);
          if (iou > bv) { bv = iou; bi = t; }
        }
        #pragma unroll
        for (int t = O - 1; t >= 0; t--)
          if (bpd[t] == d) { bi = t; break; }
        int cls = (int)tl[bi] + 1;
        posBuf[b * 256 + rank] = d | (cls << 14) | (bi << 19);
      }
    }
  }
  __syncthreads();

  // ---- phase 4: radix top-k over sce (k = 3*npos), sum selected ----
  int k = npos * 3;
  if (k > D) k = D;
  unsigned prefix = 0; int kk = k;
  for (int pass = 0; pass < 4; pass++) {
    int shift = 24 - 8 * pass;
    for (int i = tid; i < 16 * 256; i += 1024) ((int*)whist)[i] = 0;
    __syncthreads();
    unsigned himask = (pass == 0) ? 0u : (0xFFFFFFFFu << (shift + 8));
    for (int d = tid; d < D; d += 1024) {
      unsigned keyb = __float_as_uint(sce[d]);
      if ((keyb & himask) == (prefix & himask))
        atomicAdd(&whist[wav][(keyb >> shift) & 255], 1);
    }
    __syncthreads();
    if (tid < 256) {
      int h = 0;
      #pragma unroll
      for (int w = 0; w < 16; w++) h += whist[w][tid];
      hist[tid] = h;
    }
    __syncthreads();
    if (tid < 64) {
      int l = tid;
      int h0 = hist[l*4], h1 = hist[l*4+1], h2 = hist[l*4+2], h3 = hist[l*4+3];
      int loc4 = h0 + h1 + h2 + h3;
      int suf = loc4;
      #pragma unroll
      for (int s = 1; s < 64; s <<= 1) {
        int o = __shfl_down(suf, s, 64);
        if (l + s < 64) suf += o;
      }
      int snext = suf - loc4;
      int s3 = snext + h3, s2 = s3 + h2, s1 = s2 + h1, s0 = s1 + h0;
      if (s3 >= kk && snext < kk) { sh_prefix = prefix | ((unsigned)(l*4+3) << shift); sh_k = kk - snext; }
      if (s2 >= kk && s3 < kk)    { sh_prefix = prefix | ((unsigned)(l*4+2) << shift); sh_k = kk - s3; }
      if (s1 >= kk && s2 < kk)    { sh_prefix = prefix | ((unsigned)(l*4+1) << shift); sh_k = kk - s2; }
      if (s0 >= kk && s1 < kk)    { sh_prefix = prefix | ((unsigned)(l*4+0) << shift); sh_k = kk - s1; }
    }
    __syncthreads();
    prefix = sh_prefix; kk = sh_k;
    __syncthreads();
  }
  float T = __uint_as_float(prefix);
  double sgt = 0.0; int cgt = 0;
  for (int d = tid; d < D; d += 1024) {
    float v = sce[d];
    if (__float_as_uint(v) > prefix) { sgt += (double)v; cgt++; }
  }
  double wv = waveSumD(sgt);
  double wc = waveSumD((double)cgt);
  if (lane == 0) { wsum[wav] = wv; wcnt[wav] = wc; }
  __syncthreads();
  if (tid == 0) {
    double tsg = 0, tcg = 0;
    #pragma unroll
    for (int w = 0; w < 16; w++) { tsg += wsum[w]; tcg += wcnt[w]; }
    atomicAdd(&acc->ce_neg, tsg + ((double)k - tcg) * (double)T);
  }
}

// ============ K2: gather first-256 positives' embeddings ============
__global__ __launch_bounds__(256) void k_gath(
    const float* __restrict__ line, const float* __restrict__ targets,
    const int* __restrict__ posBuf, const int* __restrict__ posCnt,
    Accum* acc, float* __restrict__ emb, float* __restrict__ nemb,
    float* __restrict__ qp, int* __restrict__ lab)
{
  __shared__ int spre[B + 1];
  __shared__ int sPc;
  int g = threadIdx.x;
  if (g == 0) {
    int s = 0;
    for (int bb = 0; bb < B; bb++) { spre[bb] = s; s += posCnt[bb]; }
    spre[B] = s;
    sPc = (s < 256) ? s : 256;
    acc->Pc = sPc;
  }
  __syncthreads();
  int Pc = sPc;
  if (g >= Pc) return;       // rows >= Pc never contribute (masked in k_pt)
  int b = 0;
  #pragma unroll
  for (int bb = 1; bb < B; bb++) if (g >= spre[bb]) b = bb;
  int r = g - spre[b];
  int packed = posBuf[b * 256 + r];
  int d   = packed & 0x3FFF;
  int cls = (packed >> 14) & 31;
  int bi  = (packed >> 19) & 7;
  size_t flat = (size_t)b * D + d;
  const float4* e4 = (const float4*)(line + flat * L);
  float4* o4 = (float4*)(emb + g * L);
  float4* n4 = (float4*)(nemb + g * L);
  float4 v[8];
  float nrm2 = 0.f;
  #pragma unroll
  for (int c = 0; c < 8; c++) {
    v[c] = e4[c];
    o4[c] = v[c];
    nrm2 += v[c].x*v[c].x + v[c].y*v[c].y + v[c].z*v[c].z + v[c].w*v[c].w;
  }
  float inv = 1.f / fmaxf(sqrtf(nrm2), 1e-12f);
  #pragma unroll
  for (int c = 0; c < 8; c++) {
    float4 t = v[c];
    t.x *= inv; t.y *= inv; t.z *= inv; t.w *= inv;
    n4[c] = t;
  }
  lab[g] = cls;
  const float* tr = targets + ((size_t)b * O + bi) * 9;
  qp[g * 3 + 0] = tr[5]; qp[g * 3 + 1] = tr[6]; qp[g * 3 + 2] = tr[7];
}

// ============ K3: fused pairwise dist/masks/desk + triplet loop ============
__global__ __launch_bounds__(256) void k_pt(
    const float* __restrict__ emb, const float* __restrict__ nemb,
    const float* __restrict__ qp, const int* __restrict__ lab, Accum* acc)
{
  __shared__ float ei[L], ni[L], qi[3];
  __shared__ int li, sPc;
  __shared__ float sd[256];
  __shared__ unsigned long long spm[4], snm[4];
  __shared__ double w1[4], w2[4], w3[4];
  int i = blockIdx.x, j = threadIdx.x;
  int lane = j & 63, wave = j >> 6;
  if (j < L) { ei[j] = emb[i * L + j]; ni[j] = nemb[i * L + j]; }
  if (j < 3) qi[j] = qp[i * 3 + j];
  if (j == 0) { li = lab[i]; sPc = acc->Pc; }
  __syncthreads();
  int Pc = sPc;
  bool vi = (i < Pc), vj = (j < Pc);
  const float4* nj4 = (const float4*)(nemb + j * L);
  const float4* ej4 = (const float4*)(emb + j * L);
  float sq = 0.f, esq = 0.f;
  #pragma unroll
  for (int c = 0; c < 8; c++) {
    float4 nn = nj4[c], ee = ej4[c];
    float d0 = ni[c*4+0] - nn.x, d1 = ni[c*4+1] - nn.y, d2 = ni[c*4+2] - nn.z, d3 = ni[c*4+3] - nn.w;
    sq += d0*d0 + d1*d1 + d2*d2 + d3*d3;
    float e0 = ei[c*4+0] - ee.x, e1 = ei[c*4+1] - ee.y, e2 = ei[c*4+2] - ee.z, e3 = ei[c*4+3] - ee.w;
    esq += e0*e0 + e1*e1 + e2*e2 + e3*e3;
  }
  float dd = sqrtf(fmaxf(sq, 1e-12f));
  sd[j] = dd;
  float qsq = 0.f;
  #pragma unroll
  for (int c = 0; c < 3; c++) { float dq = qi[c] - qp[j * 3 + c]; qsq += dq * dq; }
  bool vp = vi && vj && (i != j);
  bool same = (li == lab[j]);
  bool pp = vp && same && (dd > 0.2f);
  bool np = vp && !same && (dd < 0.8f);
  unsigned long long pb = __ballot(pp), nb = __ballot(np);
  float diff = esq - qsq;
  double dsk = pp ? (double)diff * (double)diff : 0.0;
  double dw = waveSumD(dsk);
  if (lane == 0) {
    spm[wave] = pb; snm[wave] = nb; w1[wave] = dw;
    if (pb) atomicAdd(&acc->n_pp, (unsigned long long)__popcll(pb));
    if (nb) atomicAdd(&acc->n_np, (unsigned long long)__popcll(nb));
  }
  __syncthreads();
  if (j == 0) {
    double t = w1[0] + w1[1] + w1[2] + w1[3];
    if (t != 0.0) atomicAdd(&acc->desk, t);
  }
  unsigned long long pm0 = spm[0], pm1 = spm[1], pm2 = spm[2], pm3 = spm[3];
  unsigned long long nm0 = snm[0], nm1 = snm[1], nm2 = snm[2], nm3 = snm[3];
  bool anyp = (pm0 | pm1 | pm2 | pm3) != 0ull;
  bool anyn = (nm0 | nm1 | nm2 | nm3) != 0ull;
  double s = 0.0, c = 0.0;
  if (anyp && anyn) {
    for (int idx = j; idx < 65536; idx += 256) {
      int jj = idx & 255, kx = idx >> 8;
      unsigned long long pmw = (jj < 64) ? pm0 : (jj < 128) ? pm1 : (jj < 192) ? pm2 : pm3;
      unsigned long long nmw = (kx < 64) ? nm0 : (kx < 128) ? nm1 : (kx < 192) ? nm2 : nm3;
      if (((pmw >> (jj & 63)) & 1ull) && ((nmw >> (kx & 63)) & 1ull)) {
        float x = sd[jj] - sd[kx] + 0.2f;
        if (x > 0.f) { s += (double)x; c += 1.0; }
      }
    }
  }
  double ws = waveSumD(s), wc = waveSumD(c);
  if (lane == 0) { w2[wave] = ws; w3[wave] = wc; }
  __syncthreads();
  if (j == 0) {
    double ts = w2[0] + w2[1] + w2[2] + w2[3];
    double tc = w3[0] + w3[1] + w3[2] + w3[3];
    if (ts != 0.0) atomicAdd(&acc->trip_sum, ts);
    if (tc != 0.0) atomicAdd(&acc->trip_cnt, tc);
  }
}

// ============ K4: finalize ============
__global__ void k_final(const Accum* acc, float* out) {
  double N = (acc->total_pos > 0) ? (double)acc->total_pos : 1.0;
  out[0] = (float)(acc->loss_l / N);
  out[1] = (float)((acc->ce_pos + acc->ce_neg) / N);
  out[2] = (float)(acc->loss_p / N);
  double cnt = (acc->trip_cnt > 0.0) ? acc->trip_cnt : 1.0;
  double loss_t = acc->trip_sum / cnt;
  double npp = (acc->n_pp > 0ull) ? (double)acc->n_pp : 1.0;
  unsigned long long tot = acc->n_pp + acc->n_np;
  double denom = (tot > 0ull) ? (double)tot : 1.0;
  double Ldesk = acc->desk / npp + loss_t / denom;
  Ldesk = Ldesk / npp / 32.0;
  out[3] = (float)Ldesk;
  out[4] = (float)loss_t;
}

extern "C" void kernel_launch(void* const* d_in, const int* in_sizes, int n_in,
                              void* d_out, int out_size, void* d_ws, size_t ws_size,
                              hipStream_t stream) {
  const float* loc     = (const float*)d_in[0];
  const float* conf    = (const float*)d_in[1];
  const float* line    = (const float*)d_in[2];
  const float* pose    = (const float*)d_in[3];
  const float* dbox    = (const float*)d_in[4];
  const float* targets = (const float*)d_in[5];
  float* out = (float*)d_out;

  char* ws = (char*)d_ws;
  size_t off = 0;
  auto alloc = [&](size_t bytes) -> char* {
    char* p = ws + off;
    off += (bytes + 255) & ~(size_t)255;
    return p;
  };
  Accum* acc    = (Accum*)alloc(sizeof(Accum));   // first 256 B: one small memset
  int* posBuf   = (int*)alloc(B * 256 * 4);
  int* posCnt   = (int*)alloc(B * 4);
  float* emb    = (float*)alloc(256 * L * 4);
  float* nemb   = (float*)alloc(256 * L * 4);
  float* qp     = (float*)alloc(256 * 3 * 4);
  int* lab      = (int*)alloc(256 * 4);

  hipMemsetAsync(acc, 0, 256, stream);
  k_fused <<<B,   1024, 0, stream>>>(loc, conf, pose, dbox, targets, posBuf, posCnt, acc);
  k_gath  <<<1,    256, 0, stream>>>(line, targets, posBuf, posCnt, acc, emb, nemb, qp, lab);
  k_pt    <<<256,  256, 0, stream>>>(emb, nemb, qp, lab, acc);
  k_final <<<1,      1, 0, stream>>>(acc, out);
}